// Round 6
// baseline (709.856 us; speedup 1.0000x reference)
//
#include <hip/hip_runtime.h>

#define NTOTAL 100000
#define NNODES 16384
#define K 32
#define S 16
#define D 190
#define E 64
#define NREL 3

__device__ float g_invn[NTOTAL];
__device__ float g_wa[384];    // [0..191] = W@a1, [192..383] = W@a2 (dims 190,191 zeroed)

// ---------- inverse L2 norms of all feature rows ----------
__global__ __launch_bounds__(256) void norms_kernel(const float* __restrict__ features) {
    const int row  = blockIdx.x * 4 + (threadIdx.x >> 6);
    const int lane = threadIdx.x & 63;
    if (row >= NTOTAL) return;
    const float2* rp = (const float2*)(features + (size_t)row * D);
    float2 a = rp[lane];
    float ss = fmaf(a.x, a.x, a.y * a.y);
    if (lane < 31) {
        float2 b = rp[64 + lane];
        ss = fmaf(b.x, b.x, fmaf(b.y, b.y, ss));
    }
    #pragma unroll
    for (int off = 32; off; off >>= 1) ss += __shfl_xor(ss, off, 64);
    if (lane == 0) g_invn[row] = 1.0f / sqrtf(ss);
}

// ---------- wa1 = W@a1, wa2 = W@a2 ----------
__global__ __launch_bounds__(192) void prep_wa(const float* __restrict__ weight,
                                               const float* __restrict__ avec) {
    const int d = threadIdx.x;              // 0..191
    float s1 = 0.f, s2 = 0.f;
    if (d < D) {
        const float* wr = weight + d * E;
        #pragma unroll 8
        for (int e = 0; e < E; ++e) {
            const float w = wr[e];
            s1 = fmaf(w, avec[e],     s1);
            s2 = fmaf(w, avec[E + e], s2);
        }
    }
    g_wa[d]       = s1;
    g_wa[192 + d] = s2;
}

// ---------- main: one WAVE per node, rows retained in registers ----------
// Lane layout for a 190-float row: lo = dims {2l,2l+1}; hi = dims {128+2l,129+2l}
// for l<31 (clamped loads for l>=31, masked by zeroing the OTHER operand).
__global__ __launch_bounds__(256, 2) void interagg_wave(
    const float* __restrict__ features,   // [N_TOTAL, D]
    const int*   __restrict__ nodes,      // [N]
    const int*   __restrict__ neigh1,     // [N, K]
    const int*   __restrict__ neigh2,
    const int*   __restrict__ neigh3,
    const float* __restrict__ weight,     // [D, E]
    float*       __restrict__ out)        // [N, E]
{
    __shared__ int   s_idx[4][96];
    __shared__ float s_sim[4][32];
    __shared__ __align__(16) float s_v[4][192];

    const int t    = threadIdx.x;
    const int lane = t & 63;
    const int wave = t >> 6;
    const int n    = blockIdx.x * 4 + wave;

    int*   idxw = s_idx[wave];
    float* simw = s_sim[wave];
    float* vw   = s_v[wave];

    // ---- indices -> per-wave LDS (2 coalesced loads) ----
    {
        const int v1 = (lane < 32) ? neigh1[n * K + lane] : neigh2[n * K + (lane - 32)];
        idxw[lane] = v1;
        if (lane < 32) idxw[64 + lane] = neigh3[n * K + lane];
    }

    // ---- center row -> registers ----
    const int  crow = nodes[n];
    const int  hl   = (lane < 31) ? lane : 30;     // clamped hi index (dims <=189)
    const bool hiok = (lane < 31);
    const float2* crp = (const float2*)(features + (size_t)crow * D);
    float2 c0 = crp[lane];
    float2 c1 = crp[64 + hl];
    if (!hiok) { c1.x = 0.f; c1.y = 0.f; }

    float rlx[NREL], rly[NREL], rhx[NREL], rhy[NREL];   // relu'd means (static idx)

    #pragma unroll
    for (int rel = 0; rel < NREL; ++rel) {
        const int* idz = idxw + rel * 32;

        // ---- load ALL 32 rows into registers; sims in 4 bursts of 8 ----
        float2 va[K], vb[K];
        #pragma unroll
        for (int b = 0; b < 4; ++b) {
            float iv[8], dt[8];
            #pragma unroll
            for (int i = 0; i < 8; ++i) {
                const int k = b * 8 + i;
                const int rid = idz[k];                  // uniform ds_read
                const float2* rp = (const float2*)(features + (size_t)rid * D);
                va[k] = rp[lane];
                vb[k] = rp[64 + hl];
                iv[i] = g_invn[rid];
            }
            #pragma unroll
            for (int i = 0; i < 8; ++i) {
                const int k = b * 8 + i;
                dt[i] = fmaf(c0.x, va[k].x, fmaf(c0.y, va[k].y,
                        fmaf(c1.x, vb[k].x, c1.y * vb[k].y)));
            }
            #pragma unroll
            for (int off = 32; off; off >>= 1) {
                #pragma unroll
                for (int i = 0; i < 8; ++i)
                    dt[i] += __shfl_xor(dt[i], off, 64);
            }
            if (lane == 0) {
                #pragma unroll
                for (int i = 0; i < 8; ++i)
                    simw[b * 8 + i] = dt[i] * iv[i];
            }
        }

        // ---- top-S by rank via shuffles (ties -> lower index, as lax.top_k) ----
        const float sk = simw[lane & 31];
        int rank = (lane < 32) ? 0 : 64;
        #pragma unroll
        for (int j = 0; j < K; ++j) {
            const float sj = __shfl(sk, j, 64);
            rank += (sj > sk) || (sj == sk && j < lane);
        }
        const unsigned int m = (unsigned int)__ballot(rank < S);  // wave-uniform, 16 bits

        // ---- masked mean from REGISTERS (no re-gather) ----
        float2 al = make_float2(0.f, 0.f);
        float2 ah = make_float2(0.f, 0.f);
        #pragma unroll
        for (int k = 0; k < K; ++k) {
            const float msk = (float)((m >> k) & 1u);
            al.x = fmaf(msk, va[k].x, al.x); al.y = fmaf(msk, va[k].y, al.y);
            ah.x = fmaf(msk, vb[k].x, ah.x); ah.y = fmaf(msk, vb[k].y, ah.y);
        }
        rlx[rel] = fmaxf(al.x * (1.f / S), 0.f);
        rly[rel] = fmaxf(al.y * (1.f / S), 0.f);
        rhx[rel] = fmaxf(ah.x * (1.f / S), 0.f);      // garbage for !hiok, masked below
        rhy[rel] = fmaxf(ah.y * (1.f / S), 0.f);
    }

    // ---- attention scores: e_r = center.wa1 + rmean_r.wa2 (4 interleaved reduces) ----
    float2 w1l = ((const float2*)g_wa)[lane];
    float2 w1h = ((const float2*)g_wa)[64 + hl];
    float2 w2l = ((const float2*)(g_wa + 192))[lane];
    float2 w2h = ((const float2*)(g_wa + 192))[64 + hl];
    if (!hiok) { w1h.x = w1h.y = 0.f; w2h.x = w2h.y = 0.f; }

    float dv[4];
    dv[0] = fmaf(c0.x, w1l.x, fmaf(c0.y, w1l.y, fmaf(c1.x, w1h.x, c1.y * w1h.y)));
    #pragma unroll
    for (int r = 0; r < NREL; ++r)
        dv[1 + r] = fmaf(rlx[r], w2l.x, fmaf(rly[r], w2l.y,
                    fmaf(rhx[r], w2h.x, rhy[r] * w2h.y)));
    #pragma unroll
    for (int off = 32; off; off >>= 1) {
        #pragma unroll
        for (int i = 0; i < 4; ++i)
            dv[i] += __shfl_xor(dv[i], off, 64);
    }

    float e1 = dv[0] + dv[1], e2 = dv[0] + dv[2], e3 = dv[0] + dv[3];
    e1 = (e1 >= 0.f) ? e1 : 0.2f * e1;
    e2 = (e2 >= 0.f) ? e2 : 0.2f * e2;
    e3 = (e3 >= 0.f) ? e3 : 0.2f * e3;
    const float mx  = fmaxf(e1, fmaxf(e2, e3));
    const float x1 = expf(e1 - mx), x2 = expf(e2 - mx), x3 = expf(e3 - mx);
    const float inv = 1.f / (x1 + x2 + x3);
    const float a1w = x1 * inv, a2w = x2 * inv, a3w = x3 * inv;

    // ---- v = center + sum att_r * rmean_r ; out = relu(v @ W) (ONE matvec) ----
    float2 v_lo, v_hi;
    v_lo.x = fmaf(a1w, rlx[0], fmaf(a2w, rlx[1], fmaf(a3w, rlx[2], c0.x)));
    v_lo.y = fmaf(a1w, rly[0], fmaf(a2w, rly[1], fmaf(a3w, rly[2], c0.y)));
    v_hi.x = fmaf(a1w, rhx[0], fmaf(a2w, rhx[1], fmaf(a3w, rhx[2], c1.x)));
    v_hi.y = fmaf(a1w, rhy[0], fmaf(a2w, rhy[1], fmaf(a3w, rhy[2], c1.y)));

    ((float2*)vw)[lane] = v_lo;
    if (hiok) ((float2*)vw)[64 + lane] = v_hi;            // dims 190,191 never read

    float acc = 0.f;
    const float* wcol = weight + lane;
    #pragma unroll 4
    for (int d4 = 0; d4 < 47; ++d4) {                     // dims 0..187
        const float4 vv = *((const float4*)vw + d4);      // uniform b128 broadcast
        const int d = d4 * 4;
        acc = fmaf(vv.x, wcol[(d    ) * E], acc);
        acc = fmaf(vv.y, wcol[(d + 1) * E], acc);
        acc = fmaf(vv.z, wcol[(d + 2) * E], acc);
        acc = fmaf(vv.w, wcol[(d + 3) * E], acc);
    }
    {                                                     // dims 188,189
        const float2 vv2 = *((const float2*)vw + 94);
        acc = fmaf(vv2.x, wcol[188 * E], acc);
        acc = fmaf(vv2.y, wcol[189 * E], acc);
    }
    out[(size_t)n * E + lane] = fmaxf(acc, 0.f);
}

extern "C" void kernel_launch(void* const* d_in, const int* in_sizes, int n_in,
                              void* d_out, int out_size, void* d_ws, size_t ws_size,
                              hipStream_t stream) {
    const float* features = (const float*)d_in[0];
    const int*   nodes    = (const int*)  d_in[1];
    const int*   neigh1   = (const int*)  d_in[2];
    const int*   neigh2   = (const int*)  d_in[3];
    const int*   neigh3   = (const int*)  d_in[4];
    const float* weight   = (const float*)d_in[5];
    const float* avec     = (const float*)d_in[6];
    float*       out      = (float*)d_out;

    norms_kernel<<<NTOTAL / 4, 256, 0, stream>>>(features);
    prep_wa<<<1, 192, 0, stream>>>(weight, avec);
    interagg_wave<<<NNODES / 4, 256, 0, stream>>>(
        features, nodes, neigh1, neigh2, neigh3, weight, out);
}

// Round 7
// 397.911 us; speedup vs baseline: 1.7840x; 1.7840x over previous
//
#include <hip/hip_runtime.h>

#define NTOTAL 100000
#define NNODES 16384
#define K 32
#define S 16
#define D 190
#define E 64
#define NREL 3

__device__ float g_invn[NTOTAL];
__device__ float g_wa[384];    // [0..191] = W@a1, [192..383] = W@a2 (dims 190,191 zeroed)

// ---------- inverse L2 norms of all feature rows ----------
__global__ __launch_bounds__(256) void norms_kernel(const float* __restrict__ features) {
    const int row  = blockIdx.x * 4 + (threadIdx.x >> 6);
    const int lane = threadIdx.x & 63;
    if (row >= NTOTAL) return;
    const float2* rp = (const float2*)(features + (size_t)row * D);
    float2 a = rp[lane];
    float ss = fmaf(a.x, a.x, a.y * a.y);
    if (lane < 31) {
        float2 b = rp[64 + lane];
        ss = fmaf(b.x, b.x, fmaf(b.y, b.y, ss));
    }
    #pragma unroll
    for (int off = 32; off; off >>= 1) ss += __shfl_xor(ss, off, 64);
    if (lane == 0) g_invn[row] = 1.0f / sqrtf(ss);
}

// ---------- wa1 = W@a1, wa2 = W@a2 ----------
__global__ __launch_bounds__(192) void prep_wa(const float* __restrict__ weight,
                                               const float* __restrict__ avec) {
    const int d = threadIdx.x;              // 0..191
    float s1 = 0.f, s2 = 0.f;
    if (d < D) {
        const float* wr = weight + d * E;
        #pragma unroll 8
        for (int e = 0; e < E; ++e) {
            const float w = wr[e];
            s1 = fmaf(w, avec[e],     s1);
            s2 = fmaf(w, avec[E + e], s2);
        }
    }
    g_wa[d]       = s1;
    g_wa[192 + d] = s2;
}

// ---------- main: one WAVE per node, no __syncthreads, 8-row bursts ----------
// Lane layout for a 190-float row: lo = dims {2l,2l+1}; hi = dims {128+2l,129+2l}
// for l<31 (clamped loads for l>=31, masked by zeroing the OTHER operand).
__global__ __launch_bounds__(256, 3) void interagg_wave(
    const float* __restrict__ features,   // [N_TOTAL, D]
    const int*   __restrict__ nodes,      // [N]
    const int*   __restrict__ neigh1,     // [N, K]
    const int*   __restrict__ neigh2,
    const int*   __restrict__ neigh3,
    const float* __restrict__ weight,     // [D, E]
    float*       __restrict__ out)        // [N, E]
{
    __shared__ int   s_idx[4][96];
    __shared__ float s_sim[4][32];
    __shared__ __align__(16) float s_v[4][192];

    const int t    = threadIdx.x;
    const int lane = t & 63;
    const int wave = t >> 6;
    const int n    = blockIdx.x * 4 + wave;

    int*   idxw = s_idx[wave];
    float* simw = s_sim[wave];
    float* vw   = s_v[wave];

    // ---- indices -> per-wave LDS (2 coalesced loads) ----
    {
        const int v1 = (lane < 32) ? neigh1[n * K + lane] : neigh2[n * K + (lane - 32)];
        idxw[lane] = v1;
        if (lane < 32) idxw[64 + lane] = neigh3[n * K + lane];
    }

    // ---- center row -> registers ----
    const int  crow = nodes[n];
    const int  hl   = (lane < 31) ? lane : 30;     // clamped hi index (dims <=189)
    const bool hiok = (lane < 31);
    const float2* crp = (const float2*)(features + (size_t)crow * D);
    float2 c0 = crp[lane];
    float2 c1 = crp[64 + hl];
    if (!hiok) { c1.x = 0.f; c1.y = 0.f; }

    float rlx[NREL], rly[NREL], rhx[NREL], rhy[NREL];   // relu'd means (static idx)

    #pragma unroll
    for (int rel = 0; rel < NREL; ++rel) {
        const int* idz = idxw + rel * 32;

        // ---- sims: 4 bursts of 8 rows (raw dots; invn scaling deferred) ----
        #pragma unroll
        for (int b = 0; b < 4; ++b) {
            float2 va[8], vb[8];
            float  dt[8];
            #pragma unroll
            for (int i = 0; i < 8; ++i) {
                const int rid = idz[b * 8 + i];            // uniform ds_read
                const float2* rp = (const float2*)(features + (size_t)rid * D);
                va[i] = rp[lane];
                vb[i] = rp[64 + hl];
            }
            #pragma unroll
            for (int i = 0; i < 8; ++i)
                dt[i] = fmaf(c0.x, va[i].x, fmaf(c0.y, va[i].y,
                        fmaf(c1.x, vb[i].x, c1.y * vb[i].y)));
            #pragma unroll
            for (int off = 32; off; off >>= 1) {
                #pragma unroll
                for (int i = 0; i < 8; ++i)
                    dt[i] += __shfl_xor(dt[i], off, 64);
            }
            if (lane == 0) {
                #pragma unroll
                for (int i = 0; i < 8; ++i)
                    simw[b * 8 + i] = dt[i];
            }
        }

        // ---- scale by 1/||nf||: 32 parallel per-lane gathers ----
        if (lane < 32) simw[lane] *= g_invn[idz[lane]];

        // ---- top-S by rank via shuffles (ties -> lower index, as lax.top_k) ----
        const float sk = simw[lane & 31];
        int rank = (lane < 32) ? 0 : 64;
        #pragma unroll
        for (int j = 0; j < K; ++j) {
            const float sj = __shfl(sk, j, 64);
            rank += (sj > sk) || (sj == sk && j < lane);
        }
        unsigned int m = (unsigned int)__ballot(rank < S);  // wave-uniform, 16 bits

        // ---- mean of 16 selected rows (L2-hot re-gather), 2 bursts of 8 ----
        float2 acc_lo = make_float2(0.f, 0.f);
        float2 acc_hi = make_float2(0.f, 0.f);
        #pragma unroll
        for (int half = 0; half < 2; ++half) {
            float2 ua[8], ub[8];
            #pragma unroll
            for (int i = 0; i < 8; ++i) {
                const int k = __ffs(m) - 1; m &= m - 1;
                const int rid = idz[k];
                const float2* rp = (const float2*)(features + (size_t)rid * D);
                ua[i] = rp[lane];
                ub[i] = rp[64 + hl];
            }
            #pragma unroll
            for (int i = 0; i < 8; ++i) {
                acc_lo.x += ua[i].x; acc_lo.y += ua[i].y;
                acc_hi.x += ub[i].x; acc_hi.y += ub[i].y;
            }
        }
        rlx[rel] = fmaxf(acc_lo.x * (1.f / S), 0.f);
        rly[rel] = fmaxf(acc_lo.y * (1.f / S), 0.f);
        rhx[rel] = fmaxf(acc_hi.x * (1.f / S), 0.f);      // garbage for !hiok, masked below
        rhy[rel] = fmaxf(acc_hi.y * (1.f / S), 0.f);
    }

    // ---- attention scores: e_r = center.wa1 + rmean_r.wa2 (4 interleaved reduces) ----
    float2 w1l = ((const float2*)g_wa)[lane];
    float2 w1h = ((const float2*)g_wa)[64 + hl];
    float2 w2l = ((const float2*)(g_wa + 192))[lane];
    float2 w2h = ((const float2*)(g_wa + 192))[64 + hl];
    if (!hiok) { w1h.x = w1h.y = 0.f; w2h.x = w2h.y = 0.f; }

    float dv[4];
    dv[0] = fmaf(c0.x, w1l.x, fmaf(c0.y, w1l.y, fmaf(c1.x, w1h.x, c1.y * w1h.y)));
    #pragma unroll
    for (int r = 0; r < NREL; ++r)
        dv[1 + r] = fmaf(rlx[r], w2l.x, fmaf(rly[r], w2l.y,
                    fmaf(rhx[r], w2h.x, rhy[r] * w2h.y)));
    #pragma unroll
    for (int off = 32; off; off >>= 1) {
        #pragma unroll
        for (int i = 0; i < 4; ++i)
            dv[i] += __shfl_xor(dv[i], off, 64);
    }

    float e1 = dv[0] + dv[1], e2 = dv[0] + dv[2], e3 = dv[0] + dv[3];
    e1 = (e1 >= 0.f) ? e1 : 0.2f * e1;
    e2 = (e2 >= 0.f) ? e2 : 0.2f * e2;
    e3 = (e3 >= 0.f) ? e3 : 0.2f * e3;
    const float mx  = fmaxf(e1, fmaxf(e2, e3));
    const float x1 = expf(e1 - mx), x2 = expf(e2 - mx), x3 = expf(e3 - mx);
    const float inv = 1.f / (x1 + x2 + x3);
    const float a1w = x1 * inv, a2w = x2 * inv, a3w = x3 * inv;

    // ---- v = center + sum att_r * rmean_r ; out = relu(v @ W) (ONE matvec) ----
    float2 v_lo, v_hi;
    v_lo.x = fmaf(a1w, rlx[0], fmaf(a2w, rlx[1], fmaf(a3w, rlx[2], c0.x)));
    v_lo.y = fmaf(a1w, rly[0], fmaf(a2w, rly[1], fmaf(a3w, rly[2], c0.y)));
    v_hi.x = fmaf(a1w, rhx[0], fmaf(a2w, rhx[1], fmaf(a3w, rhx[2], c1.x)));
    v_hi.y = fmaf(a1w, rhy[0], fmaf(a2w, rhy[1], fmaf(a3w, rhy[2], c1.y)));

    ((float2*)vw)[lane] = v_lo;
    if (hiok) ((float2*)vw)[64 + lane] = v_hi;            // dims 190,191 never read

    float acc = 0.f;
    const float* wcol = weight + lane;
    #pragma unroll 4
    for (int d4 = 0; d4 < 47; ++d4) {                     // dims 0..187
        const float4 vv = *((const float4*)vw + d4);      // uniform b128 broadcast
        const int d = d4 * 4;
        acc = fmaf(vv.x, wcol[(d    ) * E], acc);
        acc = fmaf(vv.y, wcol[(d + 1) * E], acc);
        acc = fmaf(vv.z, wcol[(d + 2) * E], acc);
        acc = fmaf(vv.w, wcol[(d + 3) * E], acc);
    }
    {                                                     // dims 188,189
        const float2 vv2 = *((const float2*)vw + 94);
        acc = fmaf(vv2.x, wcol[188 * E], acc);
        acc = fmaf(vv2.y, wcol[189 * E], acc);
    }
    out[(size_t)n * E + lane] = fmaxf(acc, 0.f);
}

extern "C" void kernel_launch(void* const* d_in, const int* in_sizes, int n_in,
                              void* d_out, int out_size, void* d_ws, size_t ws_size,
                              hipStream_t stream) {
    const float* features = (const float*)d_in[0];
    const int*   nodes    = (const int*)  d_in[1];
    const int*   neigh1   = (const int*)  d_in[2];
    const int*   neigh2   = (const int*)  d_in[3];
    const int*   neigh3   = (const int*)  d_in[4];
    const float* weight   = (const float*)d_in[5];
    const float* avec     = (const float*)d_in[6];
    float*       out      = (float*)d_out;

    norms_kernel<<<NTOTAL / 4, 256, 0, stream>>>(features);
    prep_wa<<<1, 192, 0, stream>>>(weight, avec);
    interagg_wave<<<NNODES / 4, 256, 0, stream>>>(
        features, nodes, neigh1, neigh2, neigh3, weight, out);
}

// Round 8
// 319.861 us; speedup vs baseline: 2.2193x; 1.2440x over previous
//
#include <hip/hip_runtime.h>

#define NTOTAL 100000
#define NNODES 16384
#define K 32
#define S 16
#define D 190
#define E 64
#define NREL 3

__device__ float g_invn[NTOTAL];
__device__ float g_wa[384];    // [0..191] = W@a1, [192..383] = W@a2 (dims 190,191 zeroed)

// ---------- inverse L2 norms of all feature rows ----------
__global__ __launch_bounds__(256) void norms_kernel(const float* __restrict__ features) {
    const int row  = blockIdx.x * 4 + (threadIdx.x >> 6);
    const int lane = threadIdx.x & 63;
    if (row >= NTOTAL) return;
    const float2* rp = (const float2*)(features + (size_t)row * D);
    float2 a = rp[lane];
    float ss = fmaf(a.x, a.x, a.y * a.y);
    if (lane < 31) {
        float2 b = rp[64 + lane];
        ss = fmaf(b.x, b.x, fmaf(b.y, b.y, ss));
    }
    #pragma unroll
    for (int off = 32; off; off >>= 1) ss += __shfl_xor(ss, off, 64);
    if (lane == 0) g_invn[row] = 1.0f / sqrtf(ss);
}

// ---------- wa1 = W@a1, wa2 = W@a2 ----------
__global__ __launch_bounds__(192) void prep_wa(const float* __restrict__ weight,
                                               const float* __restrict__ avec) {
    const int d = threadIdx.x;              // 0..191
    float s1 = 0.f, s2 = 0.f;
    if (d < D) {
        const float* wr = weight + d * E;
        #pragma unroll 8
        for (int e = 0; e < E; ++e) {
            const float w = wr[e];
            s1 = fmaf(w, avec[e],     s1);
            s2 = fmaf(w, avec[E + e], s2);
        }
    }
    g_wa[d]       = s1;
    g_wa[192 + d] = s2;
}

// ---------- main: one WAVE per node, no __syncthreads, 8-row bursts ----------
// Lane layout for a 190-float row: lo = dims {2l,2l+1}; hi = dims {128+2l,129+2l}
// for l<31 (clamped loads for l>=31, masked by zeroing the OTHER operand).
// NOTE: no min-waves arg in launch_bounds — with it, hipcc caps VGPRs below the
// burst working set and spills ~240-900 MB to scratch (R5/R6/R7 evidence).
__global__ __launch_bounds__(256) void interagg_wave(
    const float* __restrict__ features,   // [N_TOTAL, D]
    const int*   __restrict__ nodes,      // [N]
    const int*   __restrict__ neigh1,     // [N, K]
    const int*   __restrict__ neigh2,
    const int*   __restrict__ neigh3,
    const float* __restrict__ weight,     // [D, E]
    float*       __restrict__ out)        // [N, E]
{
    __shared__ int   s_idx[4][96];
    __shared__ float s_sim[4][32];
    __shared__ __align__(16) float s_v[4][192];

    const int t    = threadIdx.x;
    const int lane = t & 63;
    const int wave = t >> 6;
    const int n    = blockIdx.x * 4 + wave;

    int*   idxw = s_idx[wave];
    float* simw = s_sim[wave];
    float* vw   = s_v[wave];

    // ---- indices -> per-wave LDS (2 coalesced loads) ----
    {
        const int v1 = (lane < 32) ? neigh1[n * K + lane] : neigh2[n * K + (lane - 32)];
        idxw[lane] = v1;
        if (lane < 32) idxw[64 + lane] = neigh3[n * K + lane];
    }

    // ---- center row -> registers ----
    const int  crow = nodes[n];
    const int  hl   = (lane < 31) ? lane : 30;     // clamped hi index (dims <=189)
    const bool hiok = (lane < 31);
    const float2* crp = (const float2*)(features + (size_t)crow * D);
    float2 c0 = crp[lane];
    float2 c1 = crp[64 + hl];
    if (!hiok) { c1.x = 0.f; c1.y = 0.f; }

    float rlx[NREL], rly[NREL], rhx[NREL], rhy[NREL];   // relu'd means (static idx)

    #pragma unroll
    for (int rel = 0; rel < NREL; ++rel) {
        const int* idz = idxw + rel * 32;

        // ---- sims: 4 bursts of 8 rows (raw dots; invn scaling deferred) ----
        #pragma unroll
        for (int b = 0; b < 4; ++b) {
            float2 va[8], vb[8];
            float  dt[8];
            #pragma unroll
            for (int i = 0; i < 8; ++i) {
                const int rid = idz[b * 8 + i];            // uniform ds_read
                const float2* rp = (const float2*)(features + (size_t)rid * D);
                va[i] = rp[lane];
                vb[i] = rp[64 + hl];
            }
            #pragma unroll
            for (int i = 0; i < 8; ++i)
                dt[i] = fmaf(c0.x, va[i].x, fmaf(c0.y, va[i].y,
                        fmaf(c1.x, vb[i].x, c1.y * vb[i].y)));
            #pragma unroll
            for (int off = 32; off; off >>= 1) {
                #pragma unroll
                for (int i = 0; i < 8; ++i)
                    dt[i] += __shfl_xor(dt[i], off, 64);
            }
            if (lane == 0) {
                #pragma unroll
                for (int i = 0; i < 8; ++i)
                    simw[b * 8 + i] = dt[i];
            }
        }

        // ---- scale by 1/||nf||: 32 parallel per-lane gathers (L2-resident table) ----
        if (lane < 32) simw[lane] *= g_invn[idz[lane]];

        // ---- top-S by rank via shuffles (ties -> lower index, as lax.top_k) ----
        const float sk = simw[lane & 31];
        int rank = (lane < 32) ? 0 : 64;
        #pragma unroll
        for (int j = 0; j < K; ++j) {
            const float sj = __shfl(sk, j, 64);
            rank += (sj > sk) || (sj == sk && j < lane);
        }
        unsigned int m = (unsigned int)__ballot(rank < S);  // wave-uniform, 16 bits

        // ---- mean of 16 selected rows (L2-hot re-gather), 2 bursts of 8 ----
        float2 acc_lo = make_float2(0.f, 0.f);
        float2 acc_hi = make_float2(0.f, 0.f);
        #pragma unroll
        for (int half = 0; half < 2; ++half) {
            float2 ua[8], ub[8];
            #pragma unroll
            for (int i = 0; i < 8; ++i) {
                const int k = __ffs(m) - 1; m &= m - 1;
                const int rid = idz[k];
                const float2* rp = (const float2*)(features + (size_t)rid * D);
                ua[i] = rp[lane];
                ub[i] = rp[64 + hl];
            }
            #pragma unroll
            for (int i = 0; i < 8; ++i) {
                acc_lo.x += ua[i].x; acc_lo.y += ua[i].y;
                acc_hi.x += ub[i].x; acc_hi.y += ub[i].y;
            }
        }
        rlx[rel] = fmaxf(acc_lo.x * (1.f / S), 0.f);
        rly[rel] = fmaxf(acc_lo.y * (1.f / S), 0.f);
        rhx[rel] = fmaxf(acc_hi.x * (1.f / S), 0.f);      // garbage for !hiok, masked below
        rhy[rel] = fmaxf(acc_hi.y * (1.f / S), 0.f);
    }

    // ---- attention scores: e_r = center.wa1 + rmean_r.wa2 (4 interleaved reduces) ----
    float2 w1l = ((const float2*)g_wa)[lane];
    float2 w1h = ((const float2*)g_wa)[64 + hl];
    float2 w2l = ((const float2*)(g_wa + 192))[lane];
    float2 w2h = ((const float2*)(g_wa + 192))[64 + hl];
    if (!hiok) { w1h.x = w1h.y = 0.f; w2h.x = w2h.y = 0.f; }

    float dv[4];
    dv[0] = fmaf(c0.x, w1l.x, fmaf(c0.y, w1l.y, fmaf(c1.x, w1h.x, c1.y * w1h.y)));
    #pragma unroll
    for (int r = 0; r < NREL; ++r)
        dv[1 + r] = fmaf(rlx[r], w2l.x, fmaf(rly[r], w2l.y,
                    fmaf(rhx[r], w2h.x, rhy[r] * w2h.y)));
    #pragma unroll
    for (int off = 32; off; off >>= 1) {
        #pragma unroll
        for (int i = 0; i < 4; ++i)
            dv[i] += __shfl_xor(dv[i], off, 64);
    }

    float e1 = dv[0] + dv[1], e2 = dv[0] + dv[2], e3 = dv[0] + dv[3];
    e1 = (e1 >= 0.f) ? e1 : 0.2f * e1;
    e2 = (e2 >= 0.f) ? e2 : 0.2f * e2;
    e3 = (e3 >= 0.f) ? e3 : 0.2f * e3;
    const float mx  = fmaxf(e1, fmaxf(e2, e3));
    const float x1 = expf(e1 - mx), x2 = expf(e2 - mx), x3 = expf(e3 - mx);
    const float inv = 1.f / (x1 + x2 + x3);
    const float a1w = x1 * inv, a2w = x2 * inv, a3w = x3 * inv;

    // ---- v = center + sum att_r * rmean_r ; out = relu(v @ W) (ONE matvec) ----
    float2 v_lo, v_hi;
    v_lo.x = fmaf(a1w, rlx[0], fmaf(a2w, rlx[1], fmaf(a3w, rlx[2], c0.x)));
    v_lo.y = fmaf(a1w, rly[0], fmaf(a2w, rly[1], fmaf(a3w, rly[2], c0.y)));
    v_hi.x = fmaf(a1w, rhx[0], fmaf(a2w, rhx[1], fmaf(a3w, rhx[2], c1.x)));
    v_hi.y = fmaf(a1w, rhy[0], fmaf(a2w, rhy[1], fmaf(a3w, rhy[2], c1.y)));

    ((float2*)vw)[lane] = v_lo;
    if (hiok) ((float2*)vw)[64 + lane] = v_hi;            // dims 190,191 never read

    float acc = 0.f;
    const float* wcol = weight + lane;
    #pragma unroll 4
    for (int d4 = 0; d4 < 47; ++d4) {                     // dims 0..187
        const float4 vv = *((const float4*)vw + d4);      // uniform b128 broadcast
        const int d = d4 * 4;
        acc = fmaf(vv.x, wcol[(d    ) * E], acc);
        acc = fmaf(vv.y, wcol[(d + 1) * E], acc);
        acc = fmaf(vv.z, wcol[(d + 2) * E], acc);
        acc = fmaf(vv.w, wcol[(d + 3) * E], acc);
    }
    {                                                     // dims 188,189
        const float2 vv2 = *((const float2*)vw + 94);
        acc = fmaf(vv2.x, wcol[188 * E], acc);
        acc = fmaf(vv2.y, wcol[189 * E], acc);
    }
    out[(size_t)n * E + lane] = fmaxf(acc, 0.f);
}

extern "C" void kernel_launch(void* const* d_in, const int* in_sizes, int n_in,
                              void* d_out, int out_size, void* d_ws, size_t ws_size,
                              hipStream_t stream) {
    const float* features = (const float*)d_in[0];
    const int*   nodes    = (const int*)  d_in[1];
    const int*   neigh1   = (const int*)  d_in[2];
    const int*   neigh2   = (const int*)  d_in[3];
    const int*   neigh3   = (const int*)  d_in[4];
    const float* weight   = (const float*)d_in[5];
    const float* avec     = (const float*)d_in[6];
    float*       out      = (float*)d_out;

    norms_kernel<<<NTOTAL / 4, 256, 0, stream>>>(features);
    prep_wa<<<1, 192, 0, stream>>>(weight, avec);
    interagg_wave<<<NNODES / 4, 256, 0, stream>>>(
        features, nodes, neigh1, neigh2, neigh3, weight, out);
}